// Round 15
// baseline (844.149 us; speedup 1.0000x reference)
//
#include <hip/hip_runtime.h>

#define SEQ   2048
#define BATCH 4096
#define HID   6
#define BLK   256   // 4 waves/block; 16 elements/block; 256 blocks -> full chip

typedef float v2f __attribute__((ext_vector_type(2)));
typedef unsigned u2 __attribute__((ext_vector_type(2)));

// ---- fast HW math ----
__device__ __forceinline__ float fexp2(float a) {
#if __has_builtin(__builtin_amdgcn_exp2f)
  return __builtin_amdgcn_exp2f(a);
#else
  float r; asm("v_exp_f32 %0, %1" : "=v"(r) : "v"(a)); return r;
#endif
}
__device__ __forceinline__ float frcp(float a) {
#if __has_builtin(__builtin_amdgcn_rcpf)
  return __builtin_amdgcn_rcpf(a);
#else
  float r; asm("v_rcp_f32 %0, %1" : "=v"(r) : "v"(a)); return r;
#endif
}

// ---- DPP row_ror:8 = p-partner exchange within 16-row (R5/R9-validated)
template <int CTRL>
__device__ __forceinline__ float dppf(float v) {
  int r = __builtin_amdgcn_update_dpp(0, __builtin_bit_cast(int, v), CTRL, 0xF, 0xF, true);
  return __builtin_bit_cast(float, r);
}

// ---- ds_swizzle broadcast of lane (8-group base + J) to the 8-group (R7/R9-validated)
// BitMode offset = (xor<<10)|(or<<5)|and ; and=0x18 keeps (layer,p) bits [4:3];
// element bit5 is outside the swizzle's 32-lane scope -> element separation free.
template <int OFF>
__device__ __forceinline__ float swzf(float v) {
  int r = __builtin_amdgcn_ds_swizzle(__builtin_bit_cast(int, v), OFF);
  return __builtin_bit_cast(float, r);
}
#define BC0 0x18
#define BC1 0x38
#define BC2 0x58
#define BC3 0x78
#define BC4 0x98
#define BC5 0xB8

// lane l <-> l^16 via v_permlane16_swap_b32 (R6/R9-validated polarity:
// lanes with bit4 set take r.x, others r.y)
__device__ __forceinline__ float xor16f(float v, bool hi) {
#if __has_builtin(__builtin_amdgcn_permlane16_swap)
  u2 r = __builtin_amdgcn_permlane16_swap(__builtin_bit_cast(unsigned, v),
                                          __builtin_bit_cast(unsigned, v), false, false);
  return __builtin_bit_cast(float, hi ? r.x : r.y);
#else
  unsigned d = __builtin_bit_cast(unsigned, v), s = d;
  asm volatile("v_permlane16_swap_b32 %0, %1" : "+v"(d), "+v"(s));
  return __builtin_bit_cast(float, hi ? d : s);
#endif
}

__device__ __forceinline__ void schedbar() {
#if __has_builtin(__builtin_amdgcn_sched_barrier)
  __builtin_amdgcn_sched_barrier(0);
#endif
}

__global__ __launch_bounds__(BLK, 1) void lstm2_kernel(
    const float* __restrict__ x,
    const float* __restrict__ Wih0, const float* __restrict__ Whh0,
    const float* __restrict__ bih0, const float* __restrict__ bhh0,
    const float* __restrict__ Wih1, const float* __restrict__ Whh1,
    const float* __restrict__ bih1, const float* __restrict__ bhh1,
    const float* __restrict__ W2,   const float* __restrict__ b2,
    float* __restrict__ out)
{
  __shared__ float obuf[64][16];   // staged output rows; flushed every 64 steps

  const int tid = threadIdx.x;
  const int wib = tid >> 6;              // wave in block 0..3
  const int l6  = tid & 63;
  const int e5  = l6 >> 5;               // element-in-stream 0..1 (bit5)
  const bool hiL = (l6 & 16) != 0;       // layer (bit4)
  const int p   = (l6 >> 3) & 1;         // gate-pair (bit3): 0={i,f} 1={g,o}
  const int u   = l6 & 7;                // unit 0..7 (6,7 pads)
  const int uu  = (u < HID) ? u : (HID - 1);
  const int elA = wib * 4 + e5;          // stream-A element within block
  const int elB = elA + 2;               // stream-B element within block
  const int bA  = blockIdx.x * 16 + elA;
  const int bB  = bA + 2;

  // ---- constants: R9-verbatim (validated, absmax 2.441e-4) ----
  const int r0 = p ? (2 * HID + uu) : uu;           // i-row or g-row
  const int r1 = p ? (3 * HID + uu) : (HID + uu);   // f-row or o-row
  const float A  = p ? 2.f : 1.f;
  const float Bc = p ? -1.f : 0.f;
  const float K0 = p ? -2.8853900817779268f : -1.4426950408889634f;
  const float K1 = -1.4426950408889634f;
  const float KT =  2.8853900817779268f;   // tanh(c) = 1 - 2*rcp(1+exp2(KT*c))

  v2f WA0[3], WA1[3], WB0[3], WB1[3];
  float BS0, BS1;
  if (!hiL) {
    WA0[0] = v2f{K0 * Wih0[r0 * 2 + 0], K0 * Wih0[r0 * 2 + 1]};
    WA1[0] = v2f{K1 * Wih0[r1 * 2 + 0], K1 * Wih0[r1 * 2 + 1]};
    WA0[1] = v2f{0.f, 0.f}; WA0[2] = v2f{0.f, 0.f};
    WA1[1] = v2f{0.f, 0.f}; WA1[2] = v2f{0.f, 0.f};
#pragma unroll
    for (int k = 0; k < 3; ++k) {
      WB0[k] = v2f{K0 * Whh0[r0 * HID + 2 * k], K0 * Whh0[r0 * HID + 2 * k + 1]};
      WB1[k] = v2f{K1 * Whh0[r1 * HID + 2 * k], K1 * Whh0[r1 * HID + 2 * k + 1]};
    }
    BS0 = K0 * (bih0[r0] + bhh0[r0]);
    BS1 = K1 * (bih0[r1] + bhh0[r1]);
  } else {
#pragma unroll
    for (int k = 0; k < 3; ++k) {
      WA0[k] = v2f{K0 * Wih1[r0 * HID + 2 * k], K0 * Wih1[r0 * HID + 2 * k + 1]};
      WA1[k] = v2f{K1 * Wih1[r1 * HID + 2 * k], K1 * Wih1[r1 * HID + 2 * k + 1]};
      WB0[k] = v2f{K0 * Whh1[r0 * HID + 2 * k], K0 * Whh1[r0 * HID + 2 * k + 1]};
      WB1[k] = v2f{K1 * Whh1[r1 * HID + 2 * k], K1 * Whh1[r1 * HID + 2 * k + 1]};
    }
    BS0 = K0 * (bih1[r0] + bhh1[r0]);
    BS1 = K1 * (bih1[r1] + bhh1[r1]);
  }
  const v2f w2p0 = v2f{W2[0], W2[1]}, w2p1 = v2f{W2[2], W2[3]}, w2p2 = v2f{W2[4], W2[5]};
  const float bout = b2[0];

  // ---- two independent streams: disjoint state + pending gather registers ----
  float hA = 0.f, cA = 0.f, hB = 0.f, cB = 0.f;
  v2f gA2[3] = {}, gA1[3] = {}, gB2[3] = {}, gB1[3] = {};

  auto gath = [&](float hv, v2f (&g)[3]) {
    g[0] = v2f{swzf<BC0>(hv), swzf<BC1>(hv)};
    g[1] = v2f{swzf<BC2>(hv), swzf<BC3>(hv)};
    g[2] = v2f{swzf<BC4>(hv), swzf<BC5>(hv)};
  };

  // compute phase: consume PREVIOUSLY-ISSUED gathers + x; advance h,c; ov = out-dot
  auto compute = [&](float& h, float& c, const v2f (&g2)[3], const v2f (&g1)[3],
                     v2f xc, float& ov) {
    v2f v10 = hiL ? g1[0] : xc;
    v2f a0v = __builtin_elementwise_fma(WA0[0], v10, v2f{BS0, 0.f});
    a0v = __builtin_elementwise_fma(WA0[1], g1[1], a0v);
    a0v = __builtin_elementwise_fma(WA0[2], g1[2], a0v);
    a0v = __builtin_elementwise_fma(WB0[0], g2[0], a0v);
    a0v = __builtin_elementwise_fma(WB0[1], g2[1], a0v);
    a0v = __builtin_elementwise_fma(WB0[2], g2[2], a0v);
    float a0 = a0v.x + a0v.y;

    v2f a1v = __builtin_elementwise_fma(WA1[0], v10, v2f{BS1, 0.f});
    a1v = __builtin_elementwise_fma(WA1[1], g1[1], a1v);
    a1v = __builtin_elementwise_fma(WA1[2], g1[2], a1v);
    a1v = __builtin_elementwise_fma(WB1[0], g2[0], a1v);
    a1v = __builtin_elementwise_fma(WB1[1], g2[1], a1v);
    a1v = __builtin_elementwise_fma(WB1[2], g2[2], a1v);
    float a1 = a1v.x + a1v.y;

    v2f ao = __builtin_elementwise_fma(w2p0, g2[0],
             __builtin_elementwise_fma(w2p1, g2[1],
             __builtin_elementwise_fma(w2p2, g2[2], v2f{bout, 0.f})));
    ov = ao.x + ao.y;

    float g0  = fmaf(A, frcp(1.f + fexp2(a0)), Bc);
    float g1v = frcp(1.f + fexp2(a1));
    float xg0 = dppf<0x128>(g0);
    float xg1 = dppf<0x128>(g1v);
    float m = g0 * xg0;
    float f = p ? xg1 : g1v;
    float o = p ? g1v : xg1;
    c = fmaf(f, c, m);
    float th = fmaf(-2.f, frcp(1.f + fexp2(c * KT)), 1.f);
    h = o * th;
  };

  // issue phase: launch 12 swizzles whose results are consumed NEXT iteration
  auto issue = [&](float h, v2f (&g2)[3], v2f (&g1)[3]) {
    gath(h, g2);                 // own-layer recurrence gather
    float hs = xor16f(h, hiL);   // cross-layer handoff (L1 lanes get h0)
    gath(hs, g1);                // L1's input gather (L0 lanes: unused, weight-0)
  };

  // bulk flush: 64 rows x 16 elems as float4 per thread (full 64B lines)
  auto flush = [&](int rbase) {
    const int r = tid >> 2, jj = (tid & 3) * 4;
    float4 vv = *(const float4*)&obuf[r][jj];
    *(float4*)&out[(size_t)(rbase + r) * BATCH + blockIdx.x * 16 + jj] = vv;
  };

  const v2f* x2 = (const v2f*)x;
  // per-stream x prefetch queues, depth 4
  v2f xcA = x2[(size_t)0 * BATCH + bA], xcB = x2[(size_t)0 * BATCH + bB];
  v2f n1A = x2[(size_t)1 * BATCH + bA], n1B = x2[(size_t)1 * BATCH + bB];
  v2f n2A = x2[(size_t)2 * BATCH + bA], n2B = x2[(size_t)2 * BATCH + bB];
  v2f n3A = x2[(size_t)3 * BATCH + bA], n3B = x2[(size_t)3 * BATCH + bB];

  // ---- t = 0 peel: gathers are zero (h=0); L1 result is garbage -> reset ----
  {
    float ov;
    compute(hA, cA, gA2, gA1, xcA, ov);
    compute(hB, cB, gB2, gB1, xcB, ov);
    if (hiL) { hA = 0.f; cA = 0.f; hB = 0.f; cB = 0.f; }
    issue(hA, gA2, gA1);
    issue(hB, gB2, gB1);
    v2f fA = x2[(size_t)4 * BATCH + bA], fB = x2[(size_t)4 * BATCH + bB];
    xcA = n1A; n1A = n2A; n2A = n3A; n3A = fA;
    xcB = n1B; n1B = n2B; n2B = n3B; n3B = fB;
  }

  // ---- main loop: skewed dual-stream. computeA consumes gathers issued at t-1;
  // issueA's 12 swizzles fly during computeB (and vice versa across iterations).
#pragma unroll 1
  for (int t = 1; t < SEQ; ++t) {
    int tf = t + 4; tf = (tf < SEQ) ? tf : (SEQ - 1);
    v2f fA = x2[(size_t)tf * BATCH + bA];
    v2f fB = x2[(size_t)tf * BATCH + bB];

    float ovA, ovB;
    compute(hA, cA, gA2, gA1, xcA, ovA);
    if (t >= 2 && hiL && p == 0 && u == 0) obuf[(t - 2) & 63][elA] = ovA;
    issue(hA, gA2, gA1);
    schedbar();                  // pin: A's swizzles issued before B's compute

    compute(hB, cB, gB2, gB1, xcB, ovB);
    if (t >= 2 && hiL && p == 0 && u == 0) obuf[(t - 2) & 63][elB] = ovB;
    issue(hB, gB2, gB1);
    schedbar();                  // pin: B's swizzles issued before next computeA

    if (t >= 2 && ((t - 2) & 63) == 63) {   // uniform; once per 64 steps
      __syncthreads();
      flush(t - 2 - 63);
      __syncthreads();
    }
    xcA = n1A; n1A = n2A; n2A = n3A; n3A = fA;
    xcB = n1B; n1B = n2B; n2B = n3B; n3B = fB;
  }

  // ---- epilogue: one more compute -> h1[S-1] + row S-2; direct gather -> row S-1
  {
    float ovA, ovB;
    compute(hA, cA, gA2, gA1, xcA, ovA);
    compute(hB, cB, gB2, gB1, xcB, ovB);
    if (hiL && p == 0 && u == 0) { obuf[62][elA] = ovA; obuf[62][elB] = ovB; }
    gath(hA, gA2);
    gath(hB, gB2);
    v2f aoA = __builtin_elementwise_fma(w2p0, gA2[0],
              __builtin_elementwise_fma(w2p1, gA2[1],
              __builtin_elementwise_fma(w2p2, gA2[2], v2f{bout, 0.f})));
    v2f aoB = __builtin_elementwise_fma(w2p0, gB2[0],
              __builtin_elementwise_fma(w2p1, gB2[1],
              __builtin_elementwise_fma(w2p2, gB2[2], v2f{bout, 0.f})));
    if (hiL && p == 0 && u == 0) {
      obuf[63][elA] = aoA.x + aoA.y;
      obuf[63][elB] = aoB.x + aoB.y;
    }
    __syncthreads();
    flush(SEQ - 64);
  }
}

extern "C" void kernel_launch(void* const* d_in, const int* in_sizes, int n_in,
                              void* d_out, int out_size, void* d_ws, size_t ws_size,
                              hipStream_t stream) {
  const float* x    = (const float*)d_in[0];
  const float* Wih0 = (const float*)d_in[1];
  const float* Whh0 = (const float*)d_in[2];
  const float* bih0 = (const float*)d_in[3];
  const float* bhh0 = (const float*)d_in[4];
  const float* Wih1 = (const float*)d_in[5];
  const float* Whh1 = (const float*)d_in[6];
  const float* bih1 = (const float*)d_in[7];
  const float* bhh1 = (const float*)d_in[8];
  const float* W2   = (const float*)d_in[9];
  const float* b2   = (const float*)d_in[10];
  float* out = (float*)d_out;

  dim3 grid(BATCH / 16);   // 256 blocks x 4 waves = 1024 waves = 1 wave/SIMD
  dim3 block(BLK);
  hipLaunchKernelGGL(lstm2_kernel, grid, block, 0, stream,
                     x, Wih0, Whh0, bih0, bhh0, Wih1, Whh1, bih1, bhh1, W2, b2, out);
}